// Round 4
// baseline (423.696 us; speedup 1.0000x reference)
//
#include <hip/hip_runtime.h>
#include <math.h>

// ---------------------------------------------------------------------------
// Attention_20117626815094: c_t[b,t,d] = sum_e softmax_t(enc@dec^T)[e,t] * enc[e,d]
//   B=8, S_ENC=2048, S_DEC=2048, D=1024, fp32 in/out. f16 MFMA compute.
// Pipeline (v4 — softmax fused into the GEMMs):
//   1. conv_enc:  enc fp32 -> enc_h [e][d] f16 AND enc_hT [d][e] f16
//   2. conv_dec:  dec fp32 -> dec_h [t][d] f16
//   3. gemm1:     ST[t][e] = (enc@dec^T)^T, + per-block column-softmax
//                 partials (m, s) from the LDS transpose tile
//   4. stats_combine: merge 16 t-block partials -> q_e = m_e*L + log2(sum_e)
//   5. gemm2:     out[t][d] = exp2(ST*L - q_e) @ enc_hT^T-form
//                 (normalization applied in A-operand register staging)
// ---------------------------------------------------------------------------

typedef _Float16 half8 __attribute__((ext_vector_type(8)));
typedef _Float16 half4v __attribute__((ext_vector_type(4)));
typedef float floatx16 __attribute__((ext_vector_type(16)));

#define BM 128
#define BN 128
#define BK 64
#define LOG2E 1.44269504088896340736f

__device__ __forceinline__ void async_load16(const _Float16* g, void* l) {
  __builtin_amdgcn_global_load_lds(
      (const __attribute__((address_space(1))) void*)g,
      (__attribute__((address_space(3))) void*)l, 16, 0, 0);
}

// ---- GEMM: C = A @ Bt^T; A,Bt row-major f16, k contiguous -----------------
// TRANS: write C^T (f16) via LDS transpose + per-e-column softmax partials.
// NORM : A-operand is ST; apply exp2(x*L - q[k]) during staging.
template <typename OutT, bool TRANS, bool NORM, int RN>
__global__ __launch_bounds__(256, 4) void gemm_bt(
    const _Float16* __restrict__ A, const _Float16* __restrict__ Bt,
    OutT* __restrict__ C, const float* __restrict__ qv,
    float2* __restrict__ part, int K, long strideA, long strideB, long strideC,
    int ldA, int ldB, int ldC) {
  constexpr int CPR = BK / 8;   // 16B chunks per LDS row
  constexpr int SK = BK / 16;   // mfma k-substeps per tile
  __shared__ alignas(16) char smem[TRANS ? (128 * 136 * 2) : (2 * BM * BK * 2)];
  __shared__ float2 cred[256];
  _Float16* lds_a = (_Float16*)smem;
  _Float16* lds_b = (_Float16*)(smem + BM * BK * 2);

  const int b = blockIdx.z;
  A += (long)b * strideA;
  Bt += (long)b * strideB;
  C += (long)b * strideC;
  const float* qb = qv ? qv + (long)b * 2048 : nullptr;

  // XCD-aware swizzle: blocks with id%8==x form a compact 4(m) x RN(n) region
  const int id = blockIdx.y * gridDim.x + blockIdx.x;
  const int xcd = id & 7;
  const int l = id >> 3;
  const int m0 = ((xcd & 3) * 4 + l / RN) * BM;
  const int n0 = ((xcd >> 2) * RN + l % RN) * BN;

  const int tid = threadIdx.x;
  const int lane = tid & 63;
  const int wave = tid >> 6;
  const int l31 = lane & 31;
  const int kh = lane >> 5;
  const int wm = (wave >> 1) * 64;
  const int wn = (wave & 1) * 64;

  floatx16 acc[2][2] = {};

  for (int k0 = 0; k0 < K; k0 += BK) {
    // stage A,B tiles (16KB each): 4 chunks of 16B per thread per tile.
    // XOR-swizzle which logical k-chunk lands in each fixed LDS slot.
#pragma unroll
    for (int c = 0; c < 4; ++c) {
      const int off = c * 4096 + wave * 1024 + lane * 16;  // bytes in tile
      const int row = off >> 7;                            // 128B per row
      const int ke = (((off >> 4) & (CPR - 1)) ^ (row & (CPR - 1))) * 8;
      if constexpr (NORM) {
        // register path: load ST chunk, normalize, write to LDS
        half8 v = *(const half8*)(A + (long)(m0 + row) * ldA + k0 + ke);
        float4 q0 = *(const float4*)(qb + k0 + ke);
        float4 q1 = *(const float4*)(qb + k0 + ke + 4);
        float qf[8] = {q0.x, q0.y, q0.z, q0.w, q1.x, q1.y, q1.z, q1.w};
        half8 o;
#pragma unroll
        for (int j = 0; j < 8; ++j)
          o[j] = (_Float16)exp2f((float)v[j] * LOG2E - qf[j]);
        *(half8*)((char*)lds_a + off) = o;
      } else {
        async_load16(A + (long)(m0 + row) * ldA + k0 + ke, (char*)lds_a + off);
      }
      async_load16(Bt + (long)(n0 + row) * ldB + k0 + ke, (char*)lds_b + off);
    }
    __syncthreads();

    half8 af[2][SK], bf[2][SK];
#pragma unroll
    for (int i = 0; i < 2; ++i) {
      const int ra = wm + i * 32 + l31;
      const int rb = wn + i * 32 + l31;
#pragma unroll
      for (int s = 0; s < SK; ++s) {
        const int ck = s * 2 + kh;  // logical 16B chunk (k = ck*8 + j)
        af[i][s] = *(const half8*)((const char*)lds_a + ra * (BK * 2) +
                                   ((ck ^ (ra & (CPR - 1))) << 4));
        bf[i][s] = *(const half8*)((const char*)lds_b + rb * (BK * 2) +
                                   ((ck ^ (rb & (CPR - 1))) << 4));
      }
    }
#pragma unroll
    for (int s = 0; s < SK; ++s)
#pragma unroll
      for (int i = 0; i < 2; ++i)
#pragma unroll
        for (int j = 0; j < 2; ++j)
          acc[i][j] = __builtin_amdgcn_mfma_f32_32x32x16_f16(
              af[i][s], bf[j][s], acc[i][j], 0, 0, 0);
    __syncthreads();
  }

  // C/D layout (verified): col=lane&31, row=(reg&3)+8*(reg>>2)+4*(lane>>5)
  if constexpr (TRANS) {
    // write C^T[n][m] (f16): regs rr=0..3 are m-consecutive -> 8B LDS writes
    _Float16(*TT)[136] = (_Float16(*)[136])smem;
#pragma unroll
    for (int i = 0; i < 2; ++i)
#pragma unroll
      for (int j = 0; j < 2; ++j) {
        const int tl = wn + j * 32 + l31;
#pragma unroll
        for (int g = 0; g < 4; ++g) {
          half4v h;
#pragma unroll
          for (int rr = 0; rr < 4; ++rr) h[rr] = (_Float16)acc[i][j][g * 4 + rr];
          *(half4v*)&TT[tl][wm + i * 32 + 4 * kh + g * 8] = h;
        }
      }
    __syncthreads();
#pragma unroll
    for (int p = 0; p < 8; ++p) {
      const int idx = p * 256 + tid;
      const int tl = idx >> 4;
      const int ck = idx & 15;
      *(half8*)((_Float16*)C + (long)(n0 + tl) * ldC + m0 + ck * 8) =
          *(const half8*)&TT[tl][ck * 8];
    }
    // per-e-column online softmax partial over this block's 128 t values
    {
      const int e_l = tid & 127;
      const int th = tid >> 7;  // t-half
      float m = -1e30f, s = 0.f;
#pragma unroll 8
      for (int t = th * 64; t < th * 64 + 64; ++t) {
        const float x = (float)TT[t][e_l];
        const float m2 = fmaxf(m, x);
        s = s * __expf(m - m2) + __expf(x - m2);
        m = m2;
      }
      cred[tid] = make_float2(m, s);
      __syncthreads();
      if (tid < 128) {
        const float2 a = cred[tid];
        const float2 o = cred[tid + 128];
        const float m2 = fmaxf(a.x, o.x);
        const float ss = a.y * __expf(a.x - m2) + o.y * __expf(o.x - m2);
        part[((long)(n0 >> 7) * 8 + b) * 2048 + m0 + tid] =
            make_float2(m2, ss);
      }
    }
  } else {
#pragma unroll
    for (int i = 0; i < 2; ++i) {
      const int r_base = m0 + wm + i * 32 + 4 * kh;
#pragma unroll
      for (int j = 0; j < 2; ++j) {
        const int col = n0 + wn + j * 32 + l31;
#pragma unroll
        for (int g = 0; g < 4; ++g)
#pragma unroll
          for (int rr = 0; rr < 4; ++rr)
            C[(long)(r_base + g * 8 + rr) * ldC + col] =
                (OutT)acc[i][j][g * 4 + rr];
      }
    }
  }
}

// ---- enc convert + transpose (4x4 register micro-transpose) ---------------
__global__ __launch_bounds__(256) void conv_enc(const float* __restrict__ E,
                                                _Float16* __restrict__ Eh,
                                                _Float16* __restrict__ EhT,
                                                int Se, int D) {
  __shared__ _Float16 T[64][72];
  const int b = blockIdx.z;
  const int d0 = blockIdx.x * 64;
  const int e0 = blockIdx.y * 64;
  const float* Eb = E + (size_t)b * Se * D;
  _Float16* Ehb = Eh + (size_t)b * Se * D;
  _Float16* EhTb = EhT + (size_t)b * D * Se;
  const int tid = threadIdx.x;
  const int tx = tid & 15;
  const int ty = tid >> 4;

  half4v h[4];
#pragma unroll
  for (int r = 0; r < 4; ++r) {
    const int e = e0 + ty * 4 + r;
    float4 v = *(const float4*)(Eb + (size_t)e * D + d0 + tx * 4);
    h[r][0] = (_Float16)v.x; h[r][1] = (_Float16)v.y;
    h[r][2] = (_Float16)v.z; h[r][3] = (_Float16)v.w;
    *(half4v*)(Ehb + (size_t)e * D + d0 + tx * 4) = h[r];
  }
#pragma unroll
  for (int c = 0; c < 4; ++c) {
    half4v w;
#pragma unroll
    for (int r = 0; r < 4; ++r) w[r] = h[r][c];
    *(half4v*)&T[tx * 4 + c][ty * 4] = w;
  }
  __syncthreads();
#pragma unroll
  for (int p = 0; p < 2; ++p) {
    const int idx = tid + p * 256;
    const int row = idx >> 3;
    const int ck = idx & 7;
    *(half8*)(EhTb + (size_t)(d0 + row) * Se + e0 + ck * 8) =
        *(const half8*)&T[row][ck * 8];
  }
}

// ---- dec convert (16B stores) ---------------------------------------------
__global__ __launch_bounds__(256) void conv_dec(const float* __restrict__ X,
                                                _Float16* __restrict__ Y) {
  const size_t i = ((size_t)blockIdx.x * 256 + threadIdx.x) * 8;
  float4 a = *(const float4*)(X + i);
  float4 b = *(const float4*)(X + i + 4);
  half8 h;
  h[0] = (_Float16)a.x; h[1] = (_Float16)a.y;
  h[2] = (_Float16)a.z; h[3] = (_Float16)a.w;
  h[4] = (_Float16)b.x; h[5] = (_Float16)b.y;
  h[6] = (_Float16)b.z; h[7] = (_Float16)b.w;
  *(half8*)(Y + i) = h;
}

// ---- merge 16 t-block partials -> q_e = m_e*log2(e) + log2(sum_e) ---------
__global__ __launch_bounds__(256) void stats_combine(
    const float2* __restrict__ part, float* __restrict__ q) {
  const int idx = blockIdx.x * 256 + threadIdx.x;  // b*2048 + e, 16384 total
  const int b = idx >> 11;
  const int e = idx & 2047;
  float2 a = part[(long)b * 2048 + e];
#pragma unroll
  for (int tb = 1; tb < 16; ++tb) {
    const float2 o = part[((long)tb * 8 + b) * 2048 + e];
    const float m2 = fmaxf(a.x, o.x);
    a.y = a.y * __expf(a.x - m2) + o.y * __expf(o.x - m2);
    a.x = m2;
  }
  q[idx] = a.x * LOG2E + log2f(a.y);
}

// ---------------------------------------------------------------------------
extern "C" void kernel_launch(void* const* d_in, const int* in_sizes, int n_in,
                              void* d_out, int out_size, void* d_ws,
                              size_t ws_size, hipStream_t stream) {
  const float* enc = (const float*)d_in[0];
  const float* dec = (const float*)d_in[1];
  float* out = (float*)d_out;

  const int B = 8, SE = 2048, SD = 2048, D = 1024;
  char* ws = (char*)d_ws;
  _Float16* enc_h = (_Float16*)ws;                 // 32 MiB
  _Float16* dec_h = (_Float16*)(ws + 33554432);    // 32 MiB
  _Float16* enc_hT = (_Float16*)(ws + 67108864);   // 32 MiB
  _Float16* ST = (_Float16*)(ws + 100663296);      // 64 MiB
  float* q = (float*)(ws + 167772160);             // 64 KiB
  float2* part = (float2*)(ws + 167837696);        // 2 MiB

  conv_enc<<<dim3(D / 64, SE / 64, B), 256, 0, stream>>>(enc, enc_h, enc_hT,
                                                         SE, D);
  conv_dec<<<dim3((size_t)B * SD * D / 2048), 256, 0, stream>>>(dec, dec_h);
  // ST[t][e] = (enc_h @ dec_h^T)^T + column-softmax partials; gx=16 -> RN=8
  gemm_bt<_Float16, true, false, 8>
      <<<dim3(SD / BN, SE / BM, B), 256, 0, stream>>>(
          enc_h, dec_h, ST, nullptr, part, D, (long)SE * D, (long)SD * D,
          (long)SE * SD, D, D, SE);
  stats_combine<<<dim3(64), 256, 0, stream>>>(part, q);
  // out[t][d] = exp2(ST*L - q_e) @ enc_hT^T-form; gx=8 -> RN=4
  gemm_bt<float, false, true, 4>
      <<<dim3(D / BN, SD / BM, B), 256, 0, stream>>>(
          ST, enc_hT, out, q, nullptr, SE, (long)SD * SE, (long)D * SE,
          (long)SD * D, SE, SE, D);
}

// Round 5
// 351.746 us; speedup vs baseline: 1.2045x; 1.2045x over previous
//
#include <hip/hip_runtime.h>
#include <math.h>

// ---------------------------------------------------------------------------
// Attention_20117626815094: c_t[b,t,d] = sum_e softmax_t(enc@dec^T)[e,t] * enc[e,d]
//   B=8, S_ENC=2048, S_DEC=2048, D=1024, fp32 in/out. f16 MFMA compute.
// Pipeline (v5):
//   1. conv_enc:  enc fp32 -> enc_h [e][d] f16 AND enc_hT [d][e] f16
//   2. conv_dec:  dec fp32 -> dec_h [t][d] f16
//   3. gemm1:     ST[t][e] = (enc@dec^T)^T, + per-block column-softmax
//                 partials (m, s) reduced from the LDS transpose tile
//   4. stats_combine: merge 16 t-block partials -> q_e = m_e*L + log2(sum_e)
//   5. norm_stream: P[t][e] = exp2(ST*L - q_e)  (one pass, 128 MB stream)
//   6. gemm2:     out[t][d] = P @ enc_hT^T-form (pure async staging)
// Lesson (R4): never put sync VGPR work inside the staging loop — it kills
// the async global_load_lds pipeline (MfmaUtil 33->15%).
// ---------------------------------------------------------------------------

typedef _Float16 half8 __attribute__((ext_vector_type(8)));
typedef _Float16 half4v __attribute__((ext_vector_type(4)));
typedef float floatx16 __attribute__((ext_vector_type(16)));

#define BM 128
#define BN 128
#define BK 64
#define LOG2E 1.44269504088896340736f

__device__ __forceinline__ void async_load16(const _Float16* g, void* l) {
  __builtin_amdgcn_global_load_lds(
      (const __attribute__((address_space(1))) void*)g,
      (__attribute__((address_space(3))) void*)l, 16, 0, 0);
}

// ---- GEMM: C = A @ Bt^T; A,Bt row-major f16, k contiguous -----------------
// TRANS: write C^T (f16) via LDS transpose + per-e-column softmax partials.
template <typename OutT, bool TRANS, int RN>
__global__ __launch_bounds__(256, 4) void gemm_bt(
    const _Float16* __restrict__ A, const _Float16* __restrict__ Bt,
    OutT* __restrict__ C, float2* __restrict__ part, int K, long strideA,
    long strideB, long strideC, int ldA, int ldB, int ldC) {
  constexpr int CPR = BK / 8;   // 16B chunks per LDS row
  constexpr int SK = BK / 16;   // mfma k-substeps per tile
  __shared__ alignas(16) char smem[TRANS ? (128 * 136 * 2) : (2 * BM * BK * 2)];
  __shared__ float2 cred[TRANS ? 256 : 1];
  _Float16* lds_a = (_Float16*)smem;
  _Float16* lds_b = (_Float16*)(smem + BM * BK * 2);

  const int b = blockIdx.z;
  A += (long)b * strideA;
  Bt += (long)b * strideB;
  C += (long)b * strideC;

  // XCD-aware swizzle: blocks with id%8==x form a compact 4(m) x RN(n) region
  const int id = blockIdx.y * gridDim.x + blockIdx.x;
  const int xcd = id & 7;
  const int l = id >> 3;
  const int m0 = ((xcd & 3) * 4 + l / RN) * BM;
  const int n0 = ((xcd >> 2) * RN + l % RN) * BN;

  const int tid = threadIdx.x;
  const int lane = tid & 63;
  const int wave = tid >> 6;
  const int l31 = lane & 31;
  const int kh = lane >> 5;
  const int wm = (wave >> 1) * 64;
  const int wn = (wave & 1) * 64;

  floatx16 acc[2][2] = {};

  for (int k0 = 0; k0 < K; k0 += BK) {
    // stage A,B tiles (16KB each): 4 async 16B chunks per thread per tile.
    // XOR-swizzle which logical k-chunk lands in each fixed LDS slot.
#pragma unroll
    for (int c = 0; c < 4; ++c) {
      const int off = c * 4096 + wave * 1024 + lane * 16;  // bytes in tile
      const int row = off >> 7;                            // 128B per row
      const int ke = (((off >> 4) & (CPR - 1)) ^ (row & (CPR - 1))) * 8;
      async_load16(A + (long)(m0 + row) * ldA + k0 + ke, (char*)lds_a + off);
      async_load16(Bt + (long)(n0 + row) * ldB + k0 + ke, (char*)lds_b + off);
    }
    __syncthreads();

    half8 af[2][SK], bf[2][SK];
#pragma unroll
    for (int i = 0; i < 2; ++i) {
      const int ra = wm + i * 32 + l31;
      const int rb = wn + i * 32 + l31;
#pragma unroll
      for (int s = 0; s < SK; ++s) {
        const int ck = s * 2 + kh;  // logical 16B chunk (k = ck*8 + j)
        af[i][s] = *(const half8*)((const char*)lds_a + ra * (BK * 2) +
                                   ((ck ^ (ra & (CPR - 1))) << 4));
        bf[i][s] = *(const half8*)((const char*)lds_b + rb * (BK * 2) +
                                   ((ck ^ (rb & (CPR - 1))) << 4));
      }
    }
#pragma unroll
    for (int s = 0; s < SK; ++s)
#pragma unroll
      for (int i = 0; i < 2; ++i)
#pragma unroll
        for (int j = 0; j < 2; ++j)
          acc[i][j] = __builtin_amdgcn_mfma_f32_32x32x16_f16(
              af[i][s], bf[j][s], acc[i][j], 0, 0, 0);
    __syncthreads();
  }

  // C/D layout (verified): col=lane&31, row=(reg&3)+8*(reg>>2)+4*(lane>>5)
  if constexpr (TRANS) {
    // write C^T[n][m] (f16): regs rr=0..3 are m-consecutive -> 8B LDS writes
    _Float16(*TT)[136] = (_Float16(*)[136])smem;
#pragma unroll
    for (int i = 0; i < 2; ++i)
#pragma unroll
      for (int j = 0; j < 2; ++j) {
        const int tl = wn + j * 32 + l31;
#pragma unroll
        for (int g = 0; g < 4; ++g) {
          half4v h;
#pragma unroll
          for (int rr = 0; rr < 4; ++rr) h[rr] = (_Float16)acc[i][j][g * 4 + rr];
          *(half4v*)&TT[tl][wm + i * 32 + 4 * kh + g * 8] = h;
        }
      }
    __syncthreads();
#pragma unroll
    for (int p = 0; p < 8; ++p) {
      const int idx = p * 256 + tid;
      const int tl = idx >> 4;
      const int ck = idx & 15;
      *(half8*)((_Float16*)C + (long)(n0 + tl) * ldC + m0 + ck * 8) =
          *(const half8*)&TT[tl][ck * 8];
    }
    // per-e-column online softmax partial over this block's 128 t values
    {
      const int e_l = tid & 127;
      const int th = tid >> 7;  // t-half
      float m = -1e30f, s = 0.f;
#pragma unroll 8
      for (int t = th * 64; t < th * 64 + 64; ++t) {
        const float x = (float)TT[t][e_l];
        const float m2 = fmaxf(m, x);
        s = s * __expf(m - m2) + __expf(x - m2);
        m = m2;
      }
      cred[tid] = make_float2(m, s);
      __syncthreads();
      if (tid < 128) {
        const float2 a = cred[tid];
        const float2 o = cred[tid + 128];
        const float m2 = fmaxf(a.x, o.x);
        const float ss = a.y * __expf(a.x - m2) + o.y * __expf(o.x - m2);
        part[((long)(n0 >> 7) * 8 + b) * 2048 + m0 + tid] =
            make_float2(m2, ss);
      }
    }
  } else {
#pragma unroll
    for (int i = 0; i < 2; ++i) {
      const int r_base = m0 + wm + i * 32 + 4 * kh;
#pragma unroll
      for (int j = 0; j < 2; ++j) {
        const int col = n0 + wn + j * 32 + l31;
#pragma unroll
        for (int g = 0; g < 4; ++g)
#pragma unroll
          for (int rr = 0; rr < 4; ++rr)
            C[(long)(r_base + g * 8 + rr) * ldC + col] =
                (OutT)acc[i][j][g * 4 + rr];
      }
    }
  }
}

// ---- enc convert + transpose (4x4 register micro-transpose) ---------------
__global__ __launch_bounds__(256) void conv_enc(const float* __restrict__ E,
                                                _Float16* __restrict__ Eh,
                                                _Float16* __restrict__ EhT,
                                                int Se, int D) {
  __shared__ _Float16 T[64][72];
  const int b = blockIdx.z;
  const int d0 = blockIdx.x * 64;
  const int e0 = blockIdx.y * 64;
  const float* Eb = E + (size_t)b * Se * D;
  _Float16* Ehb = Eh + (size_t)b * Se * D;
  _Float16* EhTb = EhT + (size_t)b * D * Se;
  const int tid = threadIdx.x;
  const int tx = tid & 15;
  const int ty = tid >> 4;

  half4v h[4];
#pragma unroll
  for (int r = 0; r < 4; ++r) {
    const int e = e0 + ty * 4 + r;
    float4 v = *(const float4*)(Eb + (size_t)e * D + d0 + tx * 4);
    h[r][0] = (_Float16)v.x; h[r][1] = (_Float16)v.y;
    h[r][2] = (_Float16)v.z; h[r][3] = (_Float16)v.w;
    *(half4v*)(Ehb + (size_t)e * D + d0 + tx * 4) = h[r];
  }
#pragma unroll
  for (int c = 0; c < 4; ++c) {
    half4v w;
#pragma unroll
    for (int r = 0; r < 4; ++r) w[r] = h[r][c];
    *(half4v*)&T[tx * 4 + c][ty * 4] = w;
  }
  __syncthreads();
#pragma unroll
  for (int p = 0; p < 2; ++p) {
    const int idx = tid + p * 256;
    const int row = idx >> 3;
    const int ck = idx & 7;
    *(half8*)(EhTb + (size_t)(d0 + row) * Se + e0 + ck * 8) =
        *(const half8*)&T[row][ck * 8];
  }
}

// ---- dec convert (16B stores) ---------------------------------------------
__global__ __launch_bounds__(256) void conv_dec(const float* __restrict__ X,
                                                _Float16* __restrict__ Y) {
  const size_t i = ((size_t)blockIdx.x * 256 + threadIdx.x) * 8;
  float4 a = *(const float4*)(X + i);
  float4 b = *(const float4*)(X + i + 4);
  half8 h;
  h[0] = (_Float16)a.x; h[1] = (_Float16)a.y;
  h[2] = (_Float16)a.z; h[3] = (_Float16)a.w;
  h[4] = (_Float16)b.x; h[5] = (_Float16)b.y;
  h[6] = (_Float16)b.z; h[7] = (_Float16)b.w;
  *(half8*)(Y + i) = h;
}

// ---- merge 16 t-block partials -> q_e = m_e*log2(e) + log2(sum_e) ---------
__global__ __launch_bounds__(256) void stats_combine(
    const float2* __restrict__ part, float* __restrict__ q) {
  const int idx = blockIdx.x * 256 + threadIdx.x;  // b*2048 + e, 16384 total
  const int b = idx >> 11;
  const int e = idx & 2047;
  float2 a = part[(long)b * 2048 + e];
#pragma unroll
  for (int tb = 1; tb < 16; ++tb) {
    const float2 o = part[((long)tb * 8 + b) * 2048 + e];
    const float m2 = fmaxf(a.x, o.x);
    a.y = a.y * __expf(a.x - m2) + o.y * __expf(o.x - m2);
    a.x = m2;
  }
  q[idx] = a.x * LOG2E + log2f(a.y);
}

// ---- streaming normalize: P[t][e] = exp2(ST*L - q_e) ----------------------
// grid: (512, 8); block 256; 4 t-rows per block, q reused across rows.
__global__ __launch_bounds__(256) void norm_stream(
    const _Float16* __restrict__ ST, const float* __restrict__ q,
    _Float16* __restrict__ P) {
  const int b = blockIdx.y;
  const int t0 = blockIdx.x * 4;
  const int e = threadIdx.x * 8;
  float4 q0 = *(const float4*)(q + (size_t)b * 2048 + e);
  float4 q1 = *(const float4*)(q + (size_t)b * 2048 + e + 4);
  const float qf[8] = {q0.x, q0.y, q0.z, q0.w, q1.x, q1.y, q1.z, q1.w};
  const size_t base = ((size_t)b * 2048 + t0) * 2048 + e;
#pragma unroll
  for (int r = 0; r < 4; ++r) {
    half8 v = *(const half8*)(ST + base + (size_t)r * 2048);
    half8 o;
#pragma unroll
    for (int j = 0; j < 8; ++j)
      o[j] = (_Float16)exp2f((float)v[j] * LOG2E - qf[j]);
    *(half8*)(P + base + (size_t)r * 2048) = o;
  }
}

// ---------------------------------------------------------------------------
extern "C" void kernel_launch(void* const* d_in, const int* in_sizes, int n_in,
                              void* d_out, int out_size, void* d_ws,
                              size_t ws_size, hipStream_t stream) {
  const float* enc = (const float*)d_in[0];
  const float* dec = (const float*)d_in[1];
  float* out = (float*)d_out;

  const int B = 8, SE = 2048, SD = 2048, D = 1024;
  char* ws = (char*)d_ws;
  _Float16* enc_h = (_Float16*)ws;                 // 32 MiB (dead after gemm1)
  _Float16* dec_h = (_Float16*)(ws + 33554432);    // 32 MiB (dead after gemm1)
  _Float16* P = (_Float16*)ws;                     // 64 MiB (reuses enc/dec_h)
  _Float16* enc_hT = (_Float16*)(ws + 67108864);   // 32 MiB
  _Float16* ST = (_Float16*)(ws + 100663296);      // 64 MiB
  float* q = (float*)(ws + 167772160);             // 64 KiB
  float2* part = (float2*)(ws + 167837696);        // 2 MiB

  conv_enc<<<dim3(D / 64, SE / 64, B), 256, 0, stream>>>(enc, enc_h, enc_hT,
                                                         SE, D);
  conv_dec<<<dim3((size_t)B * SD * D / 2048), 256, 0, stream>>>(dec, dec_h);
  // ST[t][e] = (enc_h @ dec_h^T)^T + column-softmax partials; gx=16 -> RN=8
  gemm_bt<_Float16, true, 8><<<dim3(SD / BN, SE / BM, B), 256, 0, stream>>>(
      enc_h, dec_h, ST, part, D, (long)SE * D, (long)SD * D, (long)SE * SD, D,
      D, SE);
  stats_combine<<<dim3(64), 256, 0, stream>>>(part, q);
  norm_stream<<<dim3(512, B), 256, 0, stream>>>(ST, q, P);
  // out[t][d] = P @ enc_hT^T-form  (M=t, N=d, K=e); gx=8 -> RN=4
  gemm_bt<float, false, 4><<<dim3(D / BN, SD / BM, B), 256, 0, stream>>>(
      P, enc_hT, out, nullptr, SE, (long)SD * SE, (long)D * SE, (long)SD * D,
      SE, SE, D);
}

// Round 6
// 351.219 us; speedup vs baseline: 1.2064x; 1.0015x over previous
//
#include <hip/hip_runtime.h>
#include <math.h>

// ---------------------------------------------------------------------------
// Attention_20117626815094: c_t[b,t,d] = sum_e softmax_t(enc@dec^T)[e,t] * enc[e,d]
//   B=8, S_ENC=2048, S_DEC=2048, D=1024, fp32 in/out. f16 MFMA compute.
// Pipeline (v6):
//   1. conv_all:   enc fp32 -> enc_h [e][d] + enc_hT [d][e]; dec fp32 -> dec_h
//   2. gemm1:      ST[t][e] = (enc@dec^T)^T + column-softmax partials (m,s)
//   3. stats_combine: merge 16 t-block partials -> q_e = m_e*L + log2(sum_e)
//   4. norm_stream: P[t][e] = exp2(ST*L - q_e)
//   5. gemm2_wide: out[t][d] = P @ enc_hT^T-form — wide wave-tile (128x64),
//                  0.75 KB LDS-read per MFMA vs 1.0 (LDS-BW-bound theory)
// Lessons: R4 — no sync VGPR work in staging loop. R5 — plateau is LDS read
// BW (64KB/CU/iter vs 128 MFMA cyc), not bank conflicts (4%) per arithmetic.
// ---------------------------------------------------------------------------

typedef _Float16 half8 __attribute__((ext_vector_type(8)));
typedef _Float16 half4v __attribute__((ext_vector_type(4)));
typedef float floatx16 __attribute__((ext_vector_type(16)));

#define BM 128
#define BN 128
#define BK 64
#define LOG2E 1.44269504088896340736f

__device__ __forceinline__ void async_load16(const _Float16* g, void* l) {
  __builtin_amdgcn_global_load_lds(
      (const __attribute__((address_space(1))) void*)g,
      (__attribute__((address_space(3))) void*)l, 16, 0, 0);
}

// ---- GEMM1: ST = (A @ Bt^T)^T via LDS transpose + column softmax partials -
template <int RN>
__global__ __launch_bounds__(256, 4) void gemm_bt(
    const _Float16* __restrict__ A, const _Float16* __restrict__ Bt,
    _Float16* __restrict__ C, float2* __restrict__ part, int K, long strideA,
    long strideB, long strideC, int ldA, int ldB, int ldC) {
  constexpr int CPR = BK / 8;   // 16B chunks per LDS row
  constexpr int SK = BK / 16;   // mfma k-substeps per tile
  __shared__ alignas(16) char smem[128 * 136 * 2];
  __shared__ float2 cred[256];
  _Float16* lds_a = (_Float16*)smem;
  _Float16* lds_b = (_Float16*)(smem + BM * BK * 2);

  const int b = blockIdx.z;
  A += (long)b * strideA;
  Bt += (long)b * strideB;
  C += (long)b * strideC;

  // XCD-aware swizzle: blocks with id%8==x form a compact 4(m) x RN(n) region
  const int id = blockIdx.y * gridDim.x + blockIdx.x;
  const int xcd = id & 7;
  const int l = id >> 3;
  const int m0 = ((xcd & 3) * 4 + l / RN) * BM;
  const int n0 = ((xcd >> 2) * RN + l % RN) * BN;

  const int tid = threadIdx.x;
  const int lane = tid & 63;
  const int wave = tid >> 6;
  const int l31 = lane & 31;
  const int kh = lane >> 5;
  const int wm = (wave >> 1) * 64;
  const int wn = (wave & 1) * 64;

  floatx16 acc[2][2] = {};

  for (int k0 = 0; k0 < K; k0 += BK) {
#pragma unroll
    for (int c = 0; c < 4; ++c) {
      const int off = c * 4096 + wave * 1024 + lane * 16;  // bytes in tile
      const int row = off >> 7;                            // 128B per row
      const int ke = (((off >> 4) & (CPR - 1)) ^ (row & (CPR - 1))) * 8;
      async_load16(A + (long)(m0 + row) * ldA + k0 + ke, (char*)lds_a + off);
      async_load16(Bt + (long)(n0 + row) * ldB + k0 + ke, (char*)lds_b + off);
    }
    __syncthreads();

    half8 af[2][SK], bf[2][SK];
#pragma unroll
    for (int i = 0; i < 2; ++i) {
      const int ra = wm + i * 32 + l31;
      const int rb = wn + i * 32 + l31;
#pragma unroll
      for (int s = 0; s < SK; ++s) {
        const int ck = s * 2 + kh;
        af[i][s] = *(const half8*)((const char*)lds_a + ra * (BK * 2) +
                                   ((ck ^ (ra & (CPR - 1))) << 4));
        bf[i][s] = *(const half8*)((const char*)lds_b + rb * (BK * 2) +
                                   ((ck ^ (rb & (CPR - 1))) << 4));
      }
    }
#pragma unroll
    for (int s = 0; s < SK; ++s)
#pragma unroll
      for (int i = 0; i < 2; ++i)
#pragma unroll
        for (int j = 0; j < 2; ++j)
          acc[i][j] = __builtin_amdgcn_mfma_f32_32x32x16_f16(
              af[i][s], bf[j][s], acc[i][j], 0, 0, 0);
    __syncthreads();
  }

  // C/D layout (verified): col=lane&31, row=(reg&3)+8*(reg>>2)+4*(lane>>5)
  // write C^T[n][m] (f16): regs rr=0..3 are m-consecutive -> 8B LDS writes
  _Float16(*TT)[136] = (_Float16(*)[136])smem;
#pragma unroll
  for (int i = 0; i < 2; ++i)
#pragma unroll
    for (int j = 0; j < 2; ++j) {
      const int tl = wn + j * 32 + l31;
#pragma unroll
      for (int g = 0; g < 4; ++g) {
        half4v h;
#pragma unroll
        for (int rr = 0; rr < 4; ++rr) h[rr] = (_Float16)acc[i][j][g * 4 + rr];
        *(half4v*)&TT[tl][wm + i * 32 + 4 * kh + g * 8] = h;
      }
    }
  __syncthreads();
#pragma unroll
  for (int p = 0; p < 8; ++p) {
    const int idx = p * 256 + tid;
    const int tl = idx >> 4;
    const int ck = idx & 15;
    *(half8*)(C + (long)(n0 + tl) * ldC + m0 + ck * 8) =
        *(const half8*)&TT[tl][ck * 8];
  }
  // per-e-column online softmax partial over this block's 128 t values
  {
    const int e_l = tid & 127;
    const int th = tid >> 7;  // t-half
    float m = -1e30f, s = 0.f;
#pragma unroll 8
    for (int t = th * 64; t < th * 64 + 64; ++t) {
      const float x = (float)TT[t][e_l];
      const float m2 = fmaxf(m, x);
      s = s * __expf(m - m2) + __expf(x - m2);
      m = m2;
    }
    cred[tid] = make_float2(m, s);
    __syncthreads();
    if (tid < 128) {
      const float2 a = cred[tid];
      const float2 o = cred[tid + 128];
      const float m2 = fmaxf(a.x, o.x);
      const float ss = a.y * __expf(a.x - m2) + o.y * __expf(o.x - m2);
      part[((long)(n0 >> 7) * 8 + b) * 2048 + m0 + tid] = make_float2(m2, ss);
    }
  }
}

// ---- GEMM2 wide: C[m][n] = A @ Bt^T, fp32 out -----------------------------
// Block tile 256(m) x 128(n), BK=64; wave tile 128x64 = 4x2 frags of 32x32.
// LDS read per MFMA: (4+2) reads per 8 MFMA = 0.75 KB/MFMA (vs 1.0 for 2x2).
template <int RM, int RN>
__global__ __launch_bounds__(256, 2) void gemm_wide(
    const _Float16* __restrict__ A, const _Float16* __restrict__ Bt,
    float* __restrict__ C, int K, long strideA, long strideB, long strideC,
    int ldA, int ldB, int ldC) {
  __shared__ alignas(16) _Float16 lds_a[256 * 64];  // 32 KB
  __shared__ alignas(16) _Float16 lds_b[128 * 64];  // 16 KB
  const int b = blockIdx.z;
  A += (long)b * strideA;
  Bt += (long)b * strideB;
  C += (long)b * strideC;
  const int id = blockIdx.y * gridDim.x + blockIdx.x;
  const int xcd = id & 7;
  const int l = id >> 3;
  const int m0 = ((xcd & 3) * RM + l / RN) * 256;
  const int n0 = ((xcd >> 2) * RN + l % RN) * 128;
  const int tid = threadIdx.x;
  const int lane = tid & 63;
  const int wave = tid >> 6;
  const int l31 = lane & 31;
  const int kh = lane >> 5;
  const int wm = (wave >> 1) * 128;
  const int wn = (wave & 1) * 64;

  floatx16 acc[4][2] = {};

  for (int k0 = 0; k0 < K; k0 += 64) {
#pragma unroll
    for (int c = 0; c < 8; ++c) {  // A tile 32 KB
      const int off = c * 4096 + wave * 1024 + lane * 16;
      const int row = off >> 7;
      const int ke = (((off >> 4) & 7) ^ (row & 7)) * 8;
      async_load16(A + (long)(m0 + row) * ldA + k0 + ke, (char*)lds_a + off);
    }
#pragma unroll
    for (int c = 0; c < 4; ++c) {  // B tile 16 KB
      const int off = c * 4096 + wave * 1024 + lane * 16;
      const int row = off >> 7;
      const int ke = (((off >> 4) & 7) ^ (row & 7)) * 8;
      async_load16(Bt + (long)(n0 + row) * ldB + k0 + ke, (char*)lds_b + off);
    }
    __syncthreads();
#pragma unroll
    for (int s = 0; s < 4; ++s) {
      const int ck = s * 2 + kh;
      half8 af[4], bf[2];
#pragma unroll
      for (int i = 0; i < 4; ++i) {
        const int ra = wm + i * 32 + l31;
        af[i] = *(const half8*)((const char*)lds_a + ra * 128 +
                                ((ck ^ (ra & 7)) << 4));
      }
#pragma unroll
      for (int j = 0; j < 2; ++j) {
        const int rb = wn + j * 32 + l31;
        bf[j] = *(const half8*)((const char*)lds_b + rb * 128 +
                                ((ck ^ (rb & 7)) << 4));
      }
#pragma unroll
      for (int i = 0; i < 4; ++i)
#pragma unroll
        for (int j = 0; j < 2; ++j)
          acc[i][j] = __builtin_amdgcn_mfma_f32_32x32x16_f16(af[i], bf[j],
                                                             acc[i][j], 0, 0, 0);
    }
    __syncthreads();
  }

#pragma unroll
  for (int i = 0; i < 4; ++i) {
    const int r_base = m0 + wm + i * 32 + 4 * kh;
#pragma unroll
    for (int j = 0; j < 2; ++j) {
      const int col = n0 + wn + j * 32 + l31;
#pragma unroll
      for (int g = 0; g < 4; ++g)
#pragma unroll
        for (int rr = 0; rr < 4; ++rr)
          C[(long)(r_base + g * 8 + rr) * ldC + col] = acc[i][j][g * 4 + rr];
    }
  }
}

// ---- fused convert: enc (+transpose) and dec ------------------------------
// grid.x: [0,16) enc d-tiles of 64; [16,24) dec d-slabs of 128. grid.y: 64-row
// tiles. grid.z: batch.
__global__ __launch_bounds__(256) void conv_all(const float* __restrict__ E,
                                                const float* __restrict__ Dc,
                                                _Float16* __restrict__ Eh,
                                                _Float16* __restrict__ EhT,
                                                _Float16* __restrict__ Dh) {
  const int b = blockIdx.z;
  const int tid = threadIdx.x;
  if (blockIdx.x < 16) {  // ---- enc path: convert + 64x64 transpose
    __shared__ _Float16 T[64][72];
    const int d0 = blockIdx.x * 64;
    const int e0 = blockIdx.y * 64;
    const float* Eb = E + (size_t)b * 2048 * 1024;
    _Float16* Ehb = Eh + (size_t)b * 2048 * 1024;
    _Float16* EhTb = EhT + (size_t)b * 1024 * 2048;
    const int tx = tid & 15;
    const int ty = tid >> 4;
    half4v h[4];
#pragma unroll
    for (int r = 0; r < 4; ++r) {
      const int e = e0 + ty * 4 + r;
      float4 v = *(const float4*)(Eb + (size_t)e * 1024 + d0 + tx * 4);
      h[r][0] = (_Float16)v.x; h[r][1] = (_Float16)v.y;
      h[r][2] = (_Float16)v.z; h[r][3] = (_Float16)v.w;
      *(half4v*)(Ehb + (size_t)e * 1024 + d0 + tx * 4) = h[r];
    }
#pragma unroll
    for (int c = 0; c < 4; ++c) {
      half4v w;
#pragma unroll
      for (int r = 0; r < 4; ++r) w[r] = h[r][c];
      *(half4v*)&T[tx * 4 + c][ty * 4] = w;
    }
    __syncthreads();
#pragma unroll
    for (int p = 0; p < 2; ++p) {
      const int idx = tid + p * 256;
      const int row = idx >> 3;
      const int ck = idx & 7;
      *(half8*)(EhTb + (size_t)(d0 + row) * 2048 + e0 + ck * 8) =
          *(const half8*)&T[row][ck * 8];
    }
  } else {  // ---- dec path: pure convert, 64 t x 128 d per block
    const int d0 = (blockIdx.x - 16) * 128;
    const int t0 = blockIdx.y * 64;
    const float* Db = Dc + (size_t)b * 2048 * 1024;
    _Float16* Dhb = Dh + (size_t)b * 2048 * 1024;
    const int tx = tid & 15;  // 16 chunks of 8 d
    const int ty = tid >> 4;  // 16 row-groups
#pragma unroll
    for (int r = 0; r < 4; ++r) {
      const size_t o = (size_t)(t0 + ty + r * 16) * 1024 + d0 + tx * 8;
      float4 a = *(const float4*)(Db + o);
      float4 c = *(const float4*)(Db + o + 4);
      half8 h;
      h[0] = (_Float16)a.x; h[1] = (_Float16)a.y;
      h[2] = (_Float16)a.z; h[3] = (_Float16)a.w;
      h[4] = (_Float16)c.x; h[5] = (_Float16)c.y;
      h[6] = (_Float16)c.z; h[7] = (_Float16)c.w;
      *(half8*)(Dhb + o) = h;
    }
  }
}

// ---- merge 16 t-block partials -> q_e = m_e*log2(e) + log2(sum_e) ---------
__global__ __launch_bounds__(256) void stats_combine(
    const float2* __restrict__ part, float* __restrict__ q) {
  const int idx = blockIdx.x * 256 + threadIdx.x;  // b*2048 + e
  const int b = idx >> 11;
  const int e = idx & 2047;
  float2 a = part[(long)b * 2048 + e];
#pragma unroll
  for (int tb = 1; tb < 16; ++tb) {
    const float2 o = part[((long)tb * 8 + b) * 2048 + e];
    const float m2 = fmaxf(a.x, o.x);
    a.y = a.y * __expf(a.x - m2) + o.y * __expf(o.x - m2);
    a.x = m2;
  }
  q[idx] = a.x * LOG2E + log2f(a.y);
}

// ---- streaming normalize: P[t][e] = exp2(ST*L - q_e) ----------------------
// grid (128, 8); 16 t-rows per block; q loaded once per block.
__global__ __launch_bounds__(256) void norm_stream(
    const _Float16* __restrict__ ST, const float* __restrict__ q,
    _Float16* __restrict__ P) {
  const int b = blockIdx.y;
  const int t0 = blockIdx.x * 16;
  const int e = threadIdx.x * 8;
  float4 q0 = *(const float4*)(q + (size_t)b * 2048 + e);
  float4 q1 = *(const float4*)(q + (size_t)b * 2048 + e + 4);
  const float qf[8] = {q0.x, q0.y, q0.z, q0.w, q1.x, q1.y, q1.z, q1.w};
  const size_t base = ((size_t)b * 2048 + t0) * 2048 + e;
#pragma unroll 4
  for (int r = 0; r < 16; ++r) {
    half8 v = *(const half8*)(ST + base + (size_t)r * 2048);
    half8 o;
#pragma unroll
    for (int j = 0; j < 8; ++j)
      o[j] = (_Float16)exp2f((float)v[j] * LOG2E - qf[j]);
    *(half8*)(P + base + (size_t)r * 2048) = o;
  }
}

// ---------------------------------------------------------------------------
extern "C" void kernel_launch(void* const* d_in, const int* in_sizes, int n_in,
                              void* d_out, int out_size, void* d_ws,
                              size_t ws_size, hipStream_t stream) {
  const float* enc = (const float*)d_in[0];
  const float* dec = (const float*)d_in[1];
  float* out = (float*)d_out;

  const int B = 8, SE = 2048, SD = 2048, D = 1024;
  char* ws = (char*)d_ws;
  _Float16* enc_h = (_Float16*)ws;                 // 32 MiB (dead after gemm1)
  _Float16* dec_h = (_Float16*)(ws + 33554432);    // 32 MiB (dead after gemm1)
  _Float16* P = (_Float16*)ws;                     // 64 MiB (reuses enc/dec_h)
  _Float16* enc_hT = (_Float16*)(ws + 67108864);   // 32 MiB
  _Float16* ST = (_Float16*)(ws + 100663296);      // 64 MiB
  float* q = (float*)(ws + 167772160);             // 64 KiB
  float2* part = (float2*)(ws + 167837696);        // 2 MiB

  conv_all<<<dim3(24, 32, B), 256, 0, stream>>>(enc, dec, enc_h, enc_hT,
                                                dec_h);
  // ST[t][e] = (enc_h @ dec_h^T)^T + column-softmax partials; gx=16 -> RN=8
  gemm_bt<8><<<dim3(SD / BN, SE / BM, B), 256, 0, stream>>>(
      enc_h, dec_h, ST, part, D, (long)SE * D, (long)SD * D, (long)SE * SD, D,
      D, SE);
  stats_combine<<<dim3(64), 256, 0, stream>>>(part, q);
  norm_stream<<<dim3(128, B), 256, 0, stream>>>(ST, q, P);
  // out[t][d] = P @ enc_hT^T-form  (M=t 2048/256=8, N=d 1024/128=8)
  gemm_wide<2, 4><<<dim3(8, 8, B), 256, 0, stream>>>(
      P, enc_hT, out, SE, (long)SD * SE, (long)D * SE, (long)SD * D, SE, SE,
      D);
}